// Round 5
// baseline (662.061 us; speedup 1.0000x reference)
//
#include <hip/hip_runtime.h>

// MeanPoolAggregator: out[n] = W @ mean_k(features[neigh_idx[n,k]])
// R5: L2-W-bandwidth fix. Diagnosis: R2/R4 re-fetched the distributed W slice
// from L2 every node (compiler sank the "register" W loads; VGPR=88 proves it)
// = 6.4 GB L2 traffic = 185 us @ 34.5 TB/s == measured. Fix:
//   (a) amortize W reads over T=4 nodes per projection pass (6.4 GB -> 1.6 GB),
//   (b) pre-transpose W -> Wt[h][p] in d_ws so W reads are coalesced,
//   (c) wave-per-node float4 gather (16 dwordx4/lane in flight).

#define N_NODES  50000
#define N_UNIQUE 100000
#define KNEI     16
#define HID      256
#define POOL     128

#define NBLOCKS  2084
#define NPB      24          // 2084*24 = 50016 >= 50000 (tail guarded)
#define PASSES   6           // NPB / 4 nodes-per-pass

// ---- pre-kernel: Wt[h][p] = W[p][h]  (fp32, 256x128 = 128 KB in d_ws) ----
__global__ __launch_bounds__(256) void transpose_W_kernel(
    const float* __restrict__ W, float* __restrict__ Wt)
{
    int t = blockIdx.x * 256 + threadIdx.x;   // 0..32767
    if (t < POOL * HID) {
        int h = t >> 7;                       // 0..255
        int p = t & 127;                      // 0..127
        Wt[t] = W[p * HID + h];               // coalesced write, strided read
    }
}

__global__ __launch_bounds__(256, 4) void fused_meanpool_kernel(
    const int*   __restrict__ idx,    // [N_NODES][KNEI] int32
    const float* __restrict__ feats,  // [N_UNIQUE][HID]
    const float* __restrict__ Wt,     // [HID][POOL] transposed (d_ws)
    float* __restrict__ out)          // [N_NODES][POOL]
{
    __shared__ float4 mf4[4 * 64];          // [node][ch4]   4 KB
    __shared__ float4 part2[8][4][32];      // [ksl][node][og] 16 KB
    __shared__ int    idxc[NPB * KNEI];     // 1.5 KB

    const int tid  = threadIdx.x;
    const int wv   = tid >> 6;        // wave -> node-within-pass
    const int lane = tid & 63;
    const int og   = tid & 31;        // output group: p = og*4..og*4+3
    const int ksl  = tid >> 5;        // channel slice: h = ksl*32..ksl*32+31

    const int node0 = blockIdx.x * NPB;

    // ---- cache indices once (guard global OOB in the tail block) ----
    for (int j = tid; j < NPB * KNEI; j += 256) {
        int gj = node0 * KNEI + j;
        int v  = (gj < N_NODES * KNEI) ? idx[gj] : 0;
        idxc[j] = ((unsigned)v < (unsigned)N_UNIQUE) ? v : 0;
    }
    __syncthreads();

    const float4* feats4 = reinterpret_cast<const float4*>(feats);
    const float4* Wt4    = reinterpret_cast<const float4*>(Wt);

    for (int pass = 0; pass < PASSES; ++pass) {
        // ---- phase 1: wave wv gathers node (pass*4+wv); lane owns ch 4l..4l+3 ----
        {
            const int ib = pass * 64 + wv * 16;
            float4 t[KNEI];
#pragma unroll
            for (int k = 0; k < KNEI; ++k)
                t[k] = feats4[(size_t)idxc[ib + k] * 64 + lane];
#pragma unroll
            for (int s = 8; s >= 1; s >>= 1)
#pragma unroll
                for (int k = 0; k < s; ++k) {
                    t[k].x += t[k + s].x; t[k].y += t[k + s].y;
                    t[k].z += t[k + s].z; t[k].w += t[k + s].w;
                }
            mf4[wv * 64 + lane] = t[0];
        }
        __syncthreads();

        // ---- phase 2: project 4 nodes per W fetch (coalesced Wt, L2-hot) ----
        float4 acc0 = {0,0,0,0}, acc1 = {0,0,0,0}, acc2 = {0,0,0,0}, acc3 = {0,0,0,0};
#pragma unroll
        for (int j4 = 0; j4 < 8; ++j4) {
            float4 wt[4];
#pragma unroll
            for (int c = 0; c < 4; ++c)
                wt[c] = Wt4[(size_t)(ksl * 32 + j4 * 4 + c) * 32 + og];
            const float4 m0 = mf4[0 * 64 + ksl * 8 + j4];
            const float4 m1 = mf4[1 * 64 + ksl * 8 + j4];
            const float4 m2 = mf4[2 * 64 + ksl * 8 + j4];
            const float4 m3 = mf4[3 * 64 + ksl * 8 + j4];
#define PROJ(A, M)                                                  \
            A.x = fmaf(wt[0].x, M.x, A.x); A.x = fmaf(wt[1].x, M.y, A.x); \
            A.x = fmaf(wt[2].x, M.z, A.x); A.x = fmaf(wt[3].x, M.w, A.x); \
            A.y = fmaf(wt[0].y, M.x, A.y); A.y = fmaf(wt[1].y, M.y, A.y); \
            A.y = fmaf(wt[2].y, M.z, A.y); A.y = fmaf(wt[3].y, M.w, A.y); \
            A.z = fmaf(wt[0].z, M.x, A.z); A.z = fmaf(wt[1].z, M.y, A.z); \
            A.z = fmaf(wt[2].z, M.z, A.z); A.z = fmaf(wt[3].z, M.w, A.z); \
            A.w = fmaf(wt[0].w, M.x, A.w); A.w = fmaf(wt[1].w, M.y, A.w); \
            A.w = fmaf(wt[2].w, M.z, A.w); A.w = fmaf(wt[3].w, M.w, A.w);
            PROJ(acc0, m0)
            PROJ(acc1, m1)
            PROJ(acc2, m2)
            PROJ(acc3, m3)
#undef PROJ
        }
        part2[ksl][0][og] = acc0;
        part2[ksl][1][og] = acc1;
        part2[ksl][2][og] = acc2;
        part2[ksl][3][og] = acc3;
        __syncthreads();

        // ---- phase 3: reduce 8 channel-slices, scale, store (4 nodes at once) ----
        if (tid < 128) {
            const int n = tid >> 5;
            const int o = tid & 31;
            float4 s = part2[0][n][o];
#pragma unroll
            for (int k = 1; k < 8; ++k) {
                const float4 p4 = part2[k][n][o];
                s.x += p4.x; s.y += p4.y; s.z += p4.z; s.w += p4.w;
            }
            const int node = node0 + pass * 4 + n;
            if (node < N_NODES) {
                const float inv = 1.f / (float)KNEI;
                s.x *= inv; s.y *= inv; s.z *= inv; s.w *= inv;
                *reinterpret_cast<float4*>(out + (size_t)node * POOL + o * 4) = s;
            }
        }
        // no 3rd barrier: next part2 write is after next pass's phase-1 barrier,
        // which phase-3 readers only reach after finishing their reads.
    }
}

extern "C" void kernel_launch(void* const* d_in, const int* in_sizes, int n_in,
                              void* d_out, int out_size, void* d_ws, size_t ws_size,
                              hipStream_t stream) {
    const int*   idx   = (const int*)d_in[0];
    const float* feats = (const float*)d_in[1];
    const float* W     = (const float*)d_in[2];
    float* out = (float*)d_out;
    float* Wt  = (float*)d_ws;                 // 128 KB scratch

    transpose_W_kernel<<<(POOL * HID + 255) / 256, 256, 0, stream>>>(W, Wt);
    fused_meanpool_kernel<<<NBLOCKS, 256, 0, stream>>>(idx, feats, Wt, out);
}

// Round 8
// 297.766 us; speedup vs baseline: 2.2234x; 2.2234x over previous
//
#include <hip/hip_runtime.h>

// MeanPoolAggregator: out[n] = W @ mean_k(features[neigh_idx[n,k]])
//
// R6 re-resubmit (two consecutive GPU-acquisition timeouts; never executed).
// Register-pinned W. Diagnosis history:
//   R2/R4 (~175-212us): VGPR=88/104 proves compiler SANK the per-thread W
//     "register" copy -> whole W re-read from L2 every node = ~6.4 GB L2
//     traffic = ~185us @ 34.5 TB/s (matches measured). [theory under test]
//   R5 (560us): __launch_bounds__(256,4) capped VGPR at 64 -> float4 t[16]
//     gather array spilled to scratch (FETCH 389MB->1.56GB, WRITE +280MB,
//     VALUBusy 6.6%). Never tested the W theory.
// Fix: 512-thread blocks -> W slice is only 64 floats/thread (16 float4),
//   pinned with asm so it can't be rematerialized; proven R2-style scalar
//   gather; 4 nodes/pass; no VGPR cap.

#define N_NODES  50000
#define N_UNIQUE 100000
#define KNEI     16
#define HID      256
#define POOL     128

#define NBLOCKS  2500
#define NPB      20            // 2500 * 20 == 50000 exactly
#define PASSES   5             // NPB / 4 nodes per pass

__global__ __launch_bounds__(512) void fused_meanpool_kernel(
    const int*   __restrict__ idx,    // [N_NODES][KNEI] int32
    const float* __restrict__ feats,  // [N_UNIQUE][HID]
    const float* __restrict__ W,      // [POOL][HID]
    float* __restrict__ out)          // [N_NODES][POOL]
{
    __shared__ float  mf[4][HID];         // gathered sums, 4 nodes   (4 KB)
    __shared__ float4 part2[16][4][32];   // [ksl][node][og]         (32 KB)
    __shared__ int    idxc[NPB * KNEI];   //                        (1.25 KB)

    const int tid = threadIdx.x;
    const int og  = tid & 31;             // output group: p = og*4 .. og*4+3
    const int ksl = (tid >> 5) & 15;      // channel slice: h = ksl*16 .. +15
    const int ch  = tid & 255;            // gather channel
    const int sub = tid >> 8;             // gather node sub-group (0/1)

    // ---- W slice -> registers, PINNED so it cannot be sunk/rematerialized ----
    // thread owns rows og*4..og*4+3, channels ksl*16..ksl*16+15 (64 floats).
    float4 w[4][4];
#pragma unroll
    for (int e = 0; e < 4; ++e) {
        const float* wr = W + (size_t)(og * 4 + e) * HID + ksl * 16;
#pragma unroll
        for (int j4 = 0; j4 < 4; ++j4)
            w[e][j4] = *reinterpret_cast<const float4*>(wr + j4 * 4);
    }
#pragma unroll
    for (int e = 0; e < 4; ++e)
#pragma unroll
        for (int j4 = 0; j4 < 4; ++j4)
            asm volatile("" : "+v"(w[e][j4].x), "+v"(w[e][j4].y),
                              "+v"(w[e][j4].z), "+v"(w[e][j4].w));

    const int node0 = blockIdx.x * NPB;

    // ---- cache this block's indices (coalesced, once) ----
    for (int j = tid; j < NPB * KNEI; j += 512) {
        int v = idx[node0 * KNEI + j];
        idxc[j] = ((unsigned)v < (unsigned)N_UNIQUE) ? v : 0;
    }
    __syncthreads();

    for (int pass = 0; pass < PASSES; ++pass) {
        // ---- phase 1: gather 4 nodes; thread owns channel `ch` of nodes sub, sub+2 ----
#pragma unroll
        for (int j = 0; j < 2; ++j) {
            const int n = j * 2 + sub;
            const int* ip = idxc + (pass * 4 + n) * KNEI;
            float t[KNEI];
#pragma unroll
            for (int k = 0; k < KNEI; ++k)
                t[k] = feats[(size_t)ip[k] * HID + ch];   // 16 independent loads
#pragma unroll
            for (int s = 8; s >= 1; s >>= 1)
#pragma unroll
                for (int k = 0; k < s; ++k) t[k] += t[k + s];
            mf[n][ch] = t[0];
        }
        __syncthreads();

        // ---- phase 2: project 4 nodes against register-pinned W ----
        float4 acc[4];
#pragma unroll
        for (int n = 0; n < 4; ++n) acc[n] = make_float4(0.f, 0.f, 0.f, 0.f);
#pragma unroll
        for (int j4 = 0; j4 < 4; ++j4) {
#pragma unroll
            for (int n = 0; n < 4; ++n) {
                const float4 m4 =
                    *reinterpret_cast<const float4*>(&mf[n][ksl * 16 + j4 * 4]);
                acc[n].x = fmaf(w[0][j4].x, m4.x, acc[n].x);
                acc[n].x = fmaf(w[0][j4].y, m4.y, acc[n].x);
                acc[n].x = fmaf(w[0][j4].z, m4.z, acc[n].x);
                acc[n].x = fmaf(w[0][j4].w, m4.w, acc[n].x);
                acc[n].y = fmaf(w[1][j4].x, m4.x, acc[n].y);
                acc[n].y = fmaf(w[1][j4].y, m4.y, acc[n].y);
                acc[n].y = fmaf(w[1][j4].z, m4.z, acc[n].y);
                acc[n].y = fmaf(w[1][j4].w, m4.w, acc[n].y);
                acc[n].z = fmaf(w[2][j4].x, m4.x, acc[n].z);
                acc[n].z = fmaf(w[2][j4].y, m4.y, acc[n].z);
                acc[n].z = fmaf(w[2][j4].z, m4.z, acc[n].z);
                acc[n].z = fmaf(w[2][j4].w, m4.w, acc[n].z);
                acc[n].w = fmaf(w[3][j4].x, m4.x, acc[n].w);
                acc[n].w = fmaf(w[3][j4].y, m4.y, acc[n].w);
                acc[n].w = fmaf(w[3][j4].z, m4.z, acc[n].w);
                acc[n].w = fmaf(w[3][j4].w, m4.w, acc[n].w);
            }
        }
#pragma unroll
        for (int n = 0; n < 4; ++n) part2[ksl][n][og] = acc[n];
        __syncthreads();

        // ---- phase 3: reduce 16 channel-slices, scale, store ----
        if (tid < 128) {
            const int n = tid >> 5;
            const int o = tid & 31;
            float4 s = part2[0][n][o];
#pragma unroll
            for (int k = 1; k < 16; ++k) {
                const float4 p4 = part2[k][n][o];
                s.x += p4.x; s.y += p4.y; s.z += p4.z; s.w += p4.w;
            }
            const float inv = 1.f / (float)KNEI;
            s.x *= inv; s.y *= inv; s.z *= inv; s.w *= inv;
            const int node = node0 + pass * 4 + n;
            *reinterpret_cast<float4*>(out + (size_t)node * POOL + o * 4) = s;
        }
        // 2 barriers/pass is sufficient: next part2 write happens only after
        // the next pass's phase-1 barrier, which phase-3 readers must also
        // reach; mf and part2 are disjoint.
    }
}

extern "C" void kernel_launch(void* const* d_in, const int* in_sizes, int n_in,
                              void* d_out, int out_size, void* d_ws, size_t ws_size,
                              hipStream_t stream) {
    const int*   idx   = (const int*)d_in[0];
    const float* feats = (const float*)d_in[1];
    const float* W     = (const float*)d_in[2];
    float* out = (float*)d_out;

    fused_meanpool_kernel<<<NBLOCKS, 512, 0, stream>>>(idx, feats, W, out);
}